// Round 1
// baseline (830.390 us; speedup 1.0000x reference)
//
#include <hip/hip_runtime.h>
#include <math.h>

// RBF-kernel causal attention, fp32 vector-ALU flash baseline.
// B=2,H=16,N=2048,D=128. out_i = sum_{j<=i} exp(2s*q.k - s|q|^2 - s|k|^2) v_j
// No softmax normalization; logits <= 0 so no online-max rescale needed.

#define BHC   32      // B*H
#define NSEQ  2048
#define DHEAD 128
#define BM    64      // Q rows per block
#define BN    32      // KV cols per tile
#define SM_SCALE 0.08838834764831845f   // 1/sqrt(128)

#define QS_STRIDE 132   // pad: 2-way max bank alias on row reads
#define KV_STRIDE 132
#define PS_STRIDE 33    // pad: conflict-free P column reads

__device__ __forceinline__ float half_wave_reduce(float v) {
    // sum across each 32-lane half of the 64-lane wave
    v += __shfl_xor(v, 16);
    v += __shfl_xor(v, 8);
    v += __shfl_xor(v, 4);
    v += __shfl_xor(v, 2);
    v += __shfl_xor(v, 1);
    return v;
}

__global__ __launch_bounds__(256, 2)
void rbf_causal_attn_kernel(const float* __restrict__ q,
                            const float* __restrict__ k,
                            const float* __restrict__ v,
                            float* __restrict__ out) {
    __shared__ float Qs[BM * QS_STRIDE];   // 33792 B
    __shared__ float KVs[BN * KV_STRIDE];  // 16896 B (K tile, then V tile)
    __shared__ float Ps[BM * PS_STRIDE];   // 8448 B
    __shared__ float qsq_s[BM];
    __shared__ float ksq_s[BN];
    // total 59.5 KB -> 2 blocks/CU

    const int tid  = threadIdx.x;
    const int tx   = tid & 15;     // 0..15
    const int ty   = tid >> 4;     // 0..15
    const int lane = tid & 63;
    const int bh   = blockIdx.x;   // 0..31
    const int ypair = blockIdx.y;  // 0..15

    const float* qh = q   + (size_t)bh * NSEQ * DHEAD;
    const float* kh = k   + (size_t)bh * NSEQ * DHEAD;
    const float* vh = v   + (size_t)bh * NSEQ * DHEAD;
    float*       oh = out + (size_t)bh * NSEQ * DHEAD;

    // Each block does Q-tiles {y, 31-y}: (2y+2)+(2(31-y)+2)=66 KV tiles
    // per block -> perfectly balanced causal workload, 512 blocks = 2/CU.
    for (int pass = 0; pass < 2; ++pass) {
        const int m = pass ? (31 - ypair) : ypair;

        __syncthreads();  // prev pass fully done before overwriting Qs/qsq

        // ---- load Q tile (BM x D) -> LDS, compute qsq per row ----
        {
            const float4* qb4 = (const float4*)(qh + (size_t)m * BM * DHEAD);
            #pragma unroll
            for (int it = 0; it < 8; ++it) {
                int i   = tid + it * 256;          // 0..2047
                int row = i >> 5;                  // 0..63
                int d4  = i & 31;                  // 0..31
                float4 qv = qb4[i];
                *(float4*)&Qs[row * QS_STRIDE + d4 * 4] = qv;
                float ss = qv.x*qv.x + qv.y*qv.y + qv.z*qv.z + qv.w*qv.w;
                ss = half_wave_reduce(ss);         // lanes 0..31 share row
                if ((lane & 31) == 0) qsq_s[row] = SM_SCALE * ss;
            }
        }

        float oacc[4][8];
        #pragma unroll
        for (int r = 0; r < 4; ++r)
            #pragma unroll
            for (int c = 0; c < 8; ++c) oacc[r][c] = 0.f;

        const int ntiles = 2 * m + 2;  // KV tiles needed (cols <= 64m+63)
        for (int jt = 0; jt < ntiles; ++jt) {
            const int jc = jt * BN;

            __syncthreads();  // (A) prev PV done: KVs/Ps free

            // ---- load K tile -> LDS (+ksq), V tile -> registers ----
            float4 vreg[4];
            {
                const float4* kb4 = (const float4*)(kh + (size_t)jc * DHEAD);
                const float4* vb4 = (const float4*)(vh + (size_t)jc * DHEAD);
                #pragma unroll
                for (int it = 0; it < 4; ++it) {
                    int i   = tid + it * 256;      // 0..1023
                    int row = i >> 5;              // 0..31
                    int d4  = i & 31;
                    float4 kv = kb4[i];
                    vreg[it]  = vb4[i];
                    *(float4*)&KVs[row * KV_STRIDE + d4 * 4] = kv;
                    float ss = kv.x*kv.x + kv.y*kv.y + kv.z*kv.z + kv.w*kv.w;
                    ss = half_wave_reduce(ss);
                    if ((lane & 31) == 0) ksq_s[row] = SM_SCALE * ss;
                }
            }

            __syncthreads();  // (B) K tile + ksq ready

            // ---- S = Q K^T fragment: rows {ty+16rr}, cols {tx, tx+16} ----
            float sacc[4][2];
            #pragma unroll
            for (int r = 0; r < 4; ++r) { sacc[r][0] = 0.f; sacc[r][1] = 0.f; }

            #pragma unroll 8
            for (int d4 = 0; d4 < 32; ++d4) {
                float4 kf0 = *(const float4*)&KVs[tx * KV_STRIDE + d4 * 4];
                float4 kf1 = *(const float4*)&KVs[(tx + 16) * KV_STRIDE + d4 * 4];
                #pragma unroll
                for (int rr = 0; rr < 4; ++rr) {
                    float4 qf = *(const float4*)&Qs[(ty + 16 * rr) * QS_STRIDE + d4 * 4];
                    sacc[rr][0] += qf.x*kf0.x + qf.y*kf0.y + qf.z*kf0.z + qf.w*kf0.w;
                    sacc[rr][1] += qf.x*kf1.x + qf.y*kf1.y + qf.z*kf1.z + qf.w*kf1.w;
                }
            }

            // ---- logits -> exp (causal mask) ----
            float pfrag[4][2];
            const int row0 = m * BM + ty;
            #pragma unroll
            for (int rr = 0; rr < 4; ++rr) {
                const int rg = row0 + 16 * rr;
                const float qsq = qsq_s[ty + 16 * rr];
                #pragma unroll
                for (int cc = 0; cc < 2; ++cc) {
                    const int cg = jc + tx + 16 * cc;
                    float logit = 2.f * SM_SCALE * sacc[rr][cc] - qsq
                                  - ksq_s[tx + 16 * cc];
                    pfrag[rr][cc] = (cg <= rg) ? __expf(logit) : 0.f;
                }
            }

            __syncthreads();  // (C) all S-phase LDS reads done

            // ---- write P tile; overwrite K region with V tile ----
            #pragma unroll
            for (int rr = 0; rr < 4; ++rr) {
                Ps[(ty + 16 * rr) * PS_STRIDE + tx]      = pfrag[rr][0];
                Ps[(ty + 16 * rr) * PS_STRIDE + tx + 16] = pfrag[rr][1];
            }
            #pragma unroll
            for (int it = 0; it < 4; ++it) {
                int i   = tid + it * 256;
                int row = i >> 5;
                int d4  = i & 31;
                *(float4*)&KVs[row * KV_STRIDE + d4 * 4] = vreg[it];
            }

            __syncthreads();  // (D) Ps + V ready

            // ---- O += P V : rows {ty+16rr}, dcols {tx*4..+3, 64+tx*4..+3} ----
            #pragma unroll 4
            for (int j = 0; j < BN; ++j) {
                float4 vv0 = *(const float4*)&KVs[j * KV_STRIDE + tx * 4];
                float4 vv1 = *(const float4*)&KVs[j * KV_STRIDE + tx * 4 + 64];
                #pragma unroll
                for (int rr = 0; rr < 4; ++rr) {
                    float pj = Ps[(ty + 16 * rr) * PS_STRIDE + j];
                    oacc[rr][0] += pj * vv0.x;
                    oacc[rr][1] += pj * vv0.y;
                    oacc[rr][2] += pj * vv0.z;
                    oacc[rr][3] += pj * vv0.w;
                    oacc[rr][4] += pj * vv1.x;
                    oacc[rr][5] += pj * vv1.y;
                    oacc[rr][6] += pj * vv1.z;
                    oacc[rr][7] += pj * vv1.w;
                }
            }
        }

        // ---- store O tile ----
        #pragma unroll
        for (int rr = 0; rr < 4; ++rr) {
            const int rg = m * BM + ty + 16 * rr;
            float4* ob = (float4*)(oh + (size_t)rg * DHEAD);
            ob[tx]      = make_float4(oacc[rr][0], oacc[rr][1], oacc[rr][2], oacc[rr][3]);
            ob[tx + 16] = make_float4(oacc[rr][4], oacc[rr][5], oacc[rr][6], oacc[rr][7]);
        }
    }
}

extern "C" void kernel_launch(void* const* d_in, const int* in_sizes, int n_in,
                              void* d_out, int out_size, void* d_ws, size_t ws_size,
                              hipStream_t stream) {
    const float* q = (const float*)d_in[0];
    const float* k = (const float*)d_in[1];
    const float* v = (const float*)d_in[2];
    float* out = (float*)d_out;

    dim3 grid(BHC, 16);   // 32 heads x 16 balanced Q-tile pairs = 512 blocks
    dim3 block(256);
    rbf_causal_attn_kernel<<<grid, block, 0, stream>>>(q, k, v, out);
}

// Round 2
// 288.799 us; speedup vs baseline: 2.8753x; 2.8753x over previous
//
#include <hip/hip_runtime.h>
#include <math.h>

// RBF-kernel causal attention via split-bf16 MFMA (gfx950).
// S = Q.K^T computed as qh*kh + qh*kl + ql*kh (2-term bf16 split, fp32 acc)
// P = exp(2s*S - s|q|^2 - s|k|^2) masked; O = P(bf16) * V(bf16), fp32 acc.
// BM=64, BN=64, 256 thr = 4 waves, wave owns a 32x32 S quadrant.
// Q A-frags live in registers across the whole KV loop.

#define NSEQ 2048
#define DH   128
#define SM_SCALE 0.08838834764831845f

typedef __attribute__((ext_vector_type(8))) short short8;   // bf16x8 MFMA frag
typedef __attribute__((ext_vector_type(4))) float float4_;  // fp32x4 MFMA acc
typedef __attribute__((ext_vector_type(4))) unsigned uint4_;

#define KST 136   // K lds row stride (shorts): 272B -> conflict-floor reads/writes
#define VST 36    // VP row stride (u32): 144B -> 16B-aligned, conflict-free
#define PST 72    // P lds row stride (shorts): 144B -> 16B-aligned frag reads

__device__ __forceinline__ short f2bf(float x){
  union{float f; unsigned u;} a; a.f=x;
  unsigned r = a.u + 0x7fffu + ((a.u>>16)&1u);   // RNE
  return (short)(r>>16);
}
__device__ __forceinline__ float bf2f(short h){
  union{float f; unsigned u;} a; a.u=((unsigned)(unsigned short)h)<<16; return a.f;
}

__global__ __launch_bounds__(256,2)
void rbf_attn_mfma(const float* __restrict__ qg, const float* __restrict__ kg,
                   const float* __restrict__ vg, float* __restrict__ og){
  __shared__ short    Khi[64*KST];     // 17408 B
  __shared__ short    Klo[64*KST];     // 17408 B
  __shared__ unsigned VP [128*VST];    // 18432 B  V^T packed j-pairs
  __shared__ short    Pls[64*PST];     //  9216 B
  __shared__ float    qsq_s[64];
  __shared__ float    ksq_s[64];
  // total ~63 KB -> 2 blocks/CU

  const int tid=threadIdx.x;
  const int w=tid>>6, l=tid&63;
  const int wr=w>>1, wc=w&1;        // wave quadrant: rows 32*wr.., cols 32*wc..
  const int quad=l>>4, lr=l&15;
  const int bh=blockIdx.x, yp=blockIdx.y;

  const float* Qg = qg + (size_t)bh*NSEQ*DH;
  const float* Kg = kg + (size_t)bh*NSEQ*DH;
  const float* Vg = vg + (size_t)bh*NSEQ*DH;
  float*       Og = og + (size_t)bh*NSEQ*DH;

  // Q-tile pair {yp, 31-yp}: (yp+1)+(32-yp) = 33 KV tiles/block, uniform.
  for(int pass=0;pass<2;++pass){
    const int m = pass ? (31-yp) : yp;
    __syncthreads();  // prior pass LDS use fully done

    // ---- Q -> register A-fragments (hi/lo bf16) + qsq ----
    short8 qhf[2][4], qlf[2][4];
    #pragma unroll
    for(int rt=0;rt<2;++rt){
      const int grow = m*64 + 32*wr + 16*rt + lr;
      const float* qp = Qg + (size_t)grow*DH + 8*quad;
      float ss=0.f;
      #pragma unroll
      for(int ks=0;ks<4;++ks){
        float4_ a = *(const float4_*)(qp + 32*ks);
        float4_ b = *(const float4_*)(qp + 32*ks + 4);
        short8 hi, lo;
        #pragma unroll
        for(int j=0;j<4;++j){
          float fa=a[j], fb=b[j];
          short ha=f2bf(fa); hi[j]=ha;   lo[j]=f2bf(fa-bf2f(ha));
          short hb=f2bf(fb); hi[j+4]=hb; lo[j+4]=f2bf(fb-bf2f(hb));
          ss += fa*fa + fb*fb;
        }
        qhf[rt][ks]=hi; qlf[rt][ks]=lo;
      }
      ss += __shfl_xor(ss,16);
      ss += __shfl_xor(ss,32);
      if(wc==0 && quad==0) qsq_s[32*wr+16*rt+lr] = SM_SCALE*ss;
    }

    float4_ oacc[2][4];
    #pragma unroll
    for(int a=0;a<2;++a)
      #pragma unroll
      for(int b=0;b<4;++b) oacc[a][b] = (float4_)0.f;

    const int ntiles = m+1;
    for(int jt=0;jt<ntiles;++jt){
      const int jc = jt*64;
      __syncthreads();   // B1: prev tile's LDS reads done

      // ---- K tile -> Khi/Klo (bf16 split) + ksq ----
      #pragma unroll
      for(int it=0;it<4;++it){
        const int i = tid + 256*it;
        const int row = i>>4, c0 = 8*(i&15);
        const float* kp = Kg + (size_t)(jc+row)*DH + c0;
        float4_ a = *(const float4_*)kp;
        float4_ b = *(const float4_*)(kp+4);
        short8 hi, lo;
        float ss=0.f;
        #pragma unroll
        for(int j=0;j<4;++j){
          float fa=a[j], fb=b[j];
          short ha=f2bf(fa); hi[j]=ha;   lo[j]=f2bf(fa-bf2f(ha));
          short hb=f2bf(fb); hi[j+4]=hb; lo[j+4]=f2bf(fb-bf2f(hb));
          ss += fa*fa + fb*fb;
        }
        ss += __shfl_xor(ss,1); ss += __shfl_xor(ss,2);
        ss += __shfl_xor(ss,4); ss += __shfl_xor(ss,8);
        if(lr==0) ksq_s[row] = SM_SCALE*ss;
        *(short8*)&Khi[row*KST + c0] = hi;
        *(short8*)&Klo[row*KST + c0] = lo;
      }
      // ---- V tile -> VP (transposed, j-pair packed bf16) ----
      #pragma unroll
      for(int it=0;it<4;++it){
        const int u = tid + 256*it;            // 0..1023
        const int d = u & 127, jg = u >> 7;    // jg 0..7 (8 j's each)
        const float* vp = Vg + (size_t)(jc + 8*jg)*DH + d;  // coalesced column loads
        float vv[8];
        #pragma unroll
        for(int jj=0;jj<8;++jj) vv[jj] = vp[(size_t)jj*DH];
        uint4_ pk;
        #pragma unroll
        for(int p2=0;p2<4;++p2)
          pk[p2] = (unsigned)(unsigned short)f2bf(vv[2*p2]) |
                   ((unsigned)(unsigned short)f2bf(vv[2*p2+1])<<16);
        *(uint4_*)&VP[d*VST + 4*jg] = pk;
      }
      __syncthreads();   // B2: staging visible

      // ---- S = Q.K^T, 3-pass split bf16 ----
      float4_ sacc[2][2];
      #pragma unroll
      for(int a=0;a<2;++a)
        #pragma unroll
        for(int b=0;b<2;++b) sacc[a][b] = (float4_)0.f;

      #pragma unroll
      for(int ks=0;ks<4;++ks){
        short8 khf[2], klf[2];
        #pragma unroll
        for(int ct=0;ct<2;++ct){
          const int off = (32*wc + 16*ct + lr)*KST + 32*ks + 8*quad;
          khf[ct] = *(const short8*)&Khi[off];
          klf[ct] = *(const short8*)&Klo[off];
        }
        #pragma unroll
        for(int rt=0;rt<2;++rt)
          #pragma unroll
          for(int ct=0;ct<2;++ct){
            sacc[rt][ct]=__builtin_amdgcn_mfma_f32_16x16x32_bf16(qhf[rt][ks],khf[ct],sacc[rt][ct],0,0,0);
            sacc[rt][ct]=__builtin_amdgcn_mfma_f32_16x16x32_bf16(qhf[rt][ks],klf[ct],sacc[rt][ct],0,0,0);
            sacc[rt][ct]=__builtin_amdgcn_mfma_f32_16x16x32_bf16(qlf[rt][ks],khf[ct],sacc[rt][ct],0,0,0);
          }
      }

      // ---- logits -> exp -> bf16 P (LDS, A-layout transit) ----
      #pragma unroll
      for(int rt=0;rt<2;++rt){
        float qs[4];
        #pragma unroll
        for(int r=0;r<4;++r) qs[r]=qsq_s[32*wr+16*rt+4*quad+r];
        #pragma unroll
        for(int ct=0;ct<2;++ct){
          const float ksq = ksq_s[32*wc+16*ct+lr];
          const int colg = jc + 32*wc+16*ct+lr;
          #pragma unroll
          for(int r=0;r<4;++r){
            const int rowg = m*64 + 32*wr+16*rt+4*quad+r;
            float logit = (2.f*SM_SCALE)*sacc[rt][ct][r] - qs[r] - ksq;
            float p = (colg<=rowg)? __expf(logit) : 0.f;
            Pls[(32*wr+16*rt+4*quad+r)*PST + 32*wc+16*ct+lr] = f2bf(p);
          }
        }
      }
      __syncthreads();   // B3: P ready

      // ---- O += P.V ----
      #pragma unroll
      for(int ks2=0;ks2<2;++ks2){
        short8 pf[2];
        #pragma unroll
        for(int rt=0;rt<2;++rt)
          pf[rt] = *(const short8*)&Pls[(32*wr+16*rt+lr)*PST + 32*ks2 + 8*quad];
        #pragma unroll
        for(int ctv=0;ctv<4;++ctv){
          const int d = 64*wc + 16*ctv + lr;
          const short8 vf = *(const short8*)((const short*)VP + d*(2*VST) + 32*ks2 + 8*quad);
          #pragma unroll
          for(int rt=0;rt<2;++rt)
            oacc[rt][ctv]=__builtin_amdgcn_mfma_f32_16x16x32_bf16(pf[rt],vf,oacc[rt][ctv],0,0,0);
        }
      }
    }

    // ---- store O ----
    #pragma unroll
    for(int rt=0;rt<2;++rt)
      #pragma unroll
      for(int ctv=0;ctv<4;++ctv)
        #pragma unroll
        for(int r=0;r<4;++r){
          const int rowg = m*64 + 32*wr + 16*rt + 4*quad + r;
          Og[(size_t)rowg*DH + 64*wc + 16*ctv + lr] = oacc[rt][ctv][r];
        }
  }
}

extern "C" void kernel_launch(void* const* d_in, const int* in_sizes, int n_in,
                              void* d_out, int out_size, void* d_ws, size_t ws_size,
                              hipStream_t stream) {
  const float* q = (const float*)d_in[0];
  const float* k = (const float*)d_in[1];
  const float* v = (const float*)d_in[2];
  float* out = (float*)d_out;

  dim3 grid(32, 16);   // 32 (b,h) x 16 balanced Q-tile pairs = 512 blocks
  dim3 block(256);
  rbf_attn_mfma<<<grid, block, 0, stream>>>(q, k, v, out);
}

// Round 3
// 266.576 us; speedup vs baseline: 3.1150x; 1.0834x over previous
//
#include <hip/hip_runtime.h>
#include <math.h>

// RBF-kernel causal attention, MFMA, with bf16 prepass (gfx950).
// Prepass: Khi=bf16(K), Vt=bf16(V)^T [d][j], ksq  -> d_ws (once per launch).
// Main: S^T = Khi . Q^T  (2 passes: kh*qh + kh*ql  => kh*q, fp32 acc)
//       P = exp(2s*S - s|q|^2 - s|k|^2) causal-masked, bf16
//       O = P . Vt^T via MFMA, fp32 acc.
// BM=64, BN=64, 256 thr = 4 waves; wave owns S^T quadrant [32 j][32 qrow].
// LDS 45.3KB -> 3 blocks/CU.

#define NSEQ 2048
#define DH   128
#define BHC  32
#define SM_SCALE 0.08838834764831845f

typedef __attribute__((ext_vector_type(8))) short short8;
typedef __attribute__((ext_vector_type(4))) short short4_;
typedef __attribute__((ext_vector_type(4))) float float4_;

#define KST 136   // K LDS row stride (shorts): 272B -> 2-way max alias
#define VST 72    // V LDS row stride (shorts): 144B, 16B-aligned, 2-way max
#define PST 72    // P LDS row stride (shorts)

__device__ __forceinline__ short f2bf(float x){
  union{float f; unsigned u;} a; a.f=x;
  unsigned r = a.u + 0x7fffu + ((a.u>>16)&1u);   // RNE
  return (short)(r>>16);
}
__device__ __forceinline__ float bf2f(short h){
  union{float f; unsigned u;} a; a.u=((unsigned)(unsigned short)h)<<16; return a.f;
}

// ---------------- prepass: K->bf16 + ksq ; V->bf16 transposed ----------------
__global__ __launch_bounds__(256)
void prep_kv(const float* __restrict__ kg, const float* __restrict__ vg,
             short* __restrict__ khig, short* __restrict__ vtg,
             float* __restrict__ ksqg){
  const int b = blockIdx.x, tid = threadIdx.x;
  if(b < 4096){
    // K: 65536 rows x 128; 16 threads/row, 8 elems each
    const int gid = b*256 + tid;
    const int row = gid >> 4, c = gid & 15;
    const float* kp = kg + (size_t)row*DH + 8*c;
    float4_ a = *(const float4_*)kp;
    float4_ bb = *(const float4_*)(kp+4);
    short8 hi; float ss = 0.f;
    #pragma unroll
    for(int j=0;j<4;++j){
      hi[j] = f2bf(a[j]); hi[j+4] = f2bf(bb[j]);
      ss += a[j]*a[j] + bb[j]*bb[j];
    }
    *(short8*)(khig + (size_t)row*DH + 8*c) = hi;
    ss += __shfl_xor(ss,1); ss += __shfl_xor(ss,2);
    ss += __shfl_xor(ss,4); ss += __shfl_xor(ss,8);
    if(c==0) ksqg[row] = SM_SCALE*ss;
  } else {
    // V transpose: thread owns (bh, d, jgroup of 8)
    const int gid = (b-4096)*256 + tid;      // 0 .. 1048575
    const int bh = gid >> 15;
    const int r  = gid & 32767;
    const int jg = r >> 7, d = r & 127;      // coalesced reads over d
    const float* vp = vg + (size_t)bh*NSEQ*DH + (size_t)(8*jg)*DH + d;
    short8 o;
    #pragma unroll
    for(int jj=0;jj<8;++jj) o[jj] = f2bf(vp[(size_t)jj*DH]);
    *(short8*)(vtg + (size_t)bh*DH*NSEQ + (size_t)d*NSEQ + 8*jg) = o;  // L2 merges lines
  }
}

// ---------------- main kernel ----------------
__global__ __launch_bounds__(256,3)
void rbf_attn_mfma2(const float* __restrict__ qg,
                    const short* __restrict__ khig,
                    const short* __restrict__ vtg,
                    const float* __restrict__ ksqg,
                    float* __restrict__ og){
  __shared__ short Khi[64*KST];   // 17408 B
  __shared__ short VPs[128*VST];  // 18432 B
  __shared__ short Pls[64*PST];   //  9216 B
  __shared__ float ksq_s[64];     // -> 45.3 KB total, 3 blocks/CU

  const int tid=threadIdx.x;
  const int w=tid>>6, l=tid&63;
  const int wr=w>>1, wc=w&1;
  const int quad=l>>4, lr=l&15;
  const int bh=blockIdx.x, yp=blockIdx.y;

  const float* Qg = qg   + (size_t)bh*NSEQ*DH;
  const short* Kh = khig + (size_t)bh*NSEQ*DH;
  const short* Vt = vtg  + (size_t)bh*DH*NSEQ;
  const float* Ks = ksqg + (size_t)bh*NSEQ;
  float*       Og = og   + (size_t)bh*NSEQ*DH;

  // Q-tile pair {yp, 31-yp}: 33 KV tiles/block, uniform across 512 blocks.
  for(int pass=0;pass<2;++pass){
    const int m = pass ? (31-yp) : yp;
    __syncthreads();

    // ---- Q -> register frags (hi/lo bf16) + qsq in-register ----
    short8 qhf[2][4], qlf[2][4];
    float qs_reg[2];
    #pragma unroll
    for(int rt=0;rt<2;++rt){
      const int grow = m*64 + 32*wr + 16*rt + lr;
      const float* qp = Qg + (size_t)grow*DH + 8*quad;
      float ss=0.f;
      #pragma unroll
      for(int ks=0;ks<4;++ks){
        float4_ a = *(const float4_*)(qp + 32*ks);
        float4_ b = *(const float4_*)(qp + 32*ks + 4);
        short8 hi, lo;
        #pragma unroll
        for(int j=0;j<4;++j){
          float fa=a[j], fb=b[j];
          short ha=f2bf(fa); hi[j]=ha;   lo[j]=f2bf(fa-bf2f(ha));
          short hb=f2bf(fb); hi[j+4]=hb; lo[j+4]=f2bf(fb-bf2f(hb));
          ss += fa*fa + fb*fb;
        }
        qhf[rt][ks]=hi; qlf[rt][ks]=lo;
      }
      ss += __shfl_xor(ss,16);
      ss += __shfl_xor(ss,32);
      qs_reg[rt] = SM_SCALE*ss;
    }

    float4_ oacc[2][4];
    #pragma unroll
    for(int a=0;a<2;++a)
      #pragma unroll
      for(int b=0;b<4;++b) oacc[a][b] = (float4_)0.f;

    const int ntiles = m+1;
    for(int jt=0;jt<ntiles;++jt){
      const int jc = jt*64;
      __syncthreads();   // B1: prev tile's LDS reads done

      // ---- stage K tile (copy-only, 16B chunks) ----
      #pragma unroll
      for(int it=0;it<4;++it){
        const int i = tid + 256*it;
        const int row = i>>4, c = i&15;
        short8 hh = *(const short8*)(Kh + (size_t)(jc+row)*DH + 8*c);
        *(short8*)&Khi[row*KST + 8*c] = hh;
      }
      // ---- stage V tile (copy-only from pre-transposed Vt) ----
      #pragma unroll
      for(int it=0;it<4;++it){
        const int i = tid + 256*it;
        const int d = i>>3, c = i&7;
        short8 vv = *(const short8*)(Vt + (size_t)d*NSEQ + jc + 8*c);
        *(short8*)&VPs[d*VST + 8*c] = vv;
      }
      if(tid < 64) ksq_s[tid] = Ks[jc + tid];
      __syncthreads();   // B2: staging visible

      // ---- S^T = Khi . Q^T (2-pass split: kh*(qh+ql)) ----
      float4_ sacc[2][2];   // [rt=qrow tile][ct=j tile]
      #pragma unroll
      for(int a=0;a<2;++a)
        #pragma unroll
        for(int b=0;b<2;++b) sacc[a][b] = (float4_)0.f;

      #pragma unroll
      for(int ks=0;ks<4;++ks){
        short8 khf[2];
        #pragma unroll
        for(int ct=0;ct<2;++ct)
          khf[ct] = *(const short8*)&Khi[(32*wc+16*ct+lr)*KST + 32*ks + 8*quad];
        #pragma unroll
        for(int rt=0;rt<2;++rt)
          #pragma unroll
          for(int ct=0;ct<2;++ct){
            sacc[rt][ct]=__builtin_amdgcn_mfma_f32_16x16x32_bf16(khf[ct],qhf[rt][ks],sacc[rt][ct],0,0,0);
            sacc[rt][ct]=__builtin_amdgcn_mfma_f32_16x16x32_bf16(khf[ct],qlf[rt][ks],sacc[rt][ct],0,0,0);
          }
      }

      // ---- exp -> P (lane holds 4 consecutive j per q-row: b64 writes) ----
      #pragma unroll
      for(int rt=0;rt<2;++rt){
        const int rowg = m*64 + 32*wr + 16*rt + lr;
        const float qs = qs_reg[rt];
        #pragma unroll
        for(int ct=0;ct<2;++ct){
          float4_ kq = *(const float4_*)&ksq_s[32*wc + 16*ct + 4*quad];
          const int j0 = jc + 32*wc + 16*ct + 4*quad;
          short4_ pw;
          #pragma unroll
          for(int r=0;r<4;++r){
            float logit = (2.f*SM_SCALE)*sacc[rt][ct][r] - qs - kq[r];
            float p = (j0 + r <= rowg) ? __expf(logit) : 0.f;
            pw[r] = f2bf(p);
          }
          *(short4_*)&Pls[(32*wr+16*rt+lr)*PST + 32*wc + 16*ct + 4*quad] = pw;
        }
      }
      __syncthreads();   // B3: P ready

      // ---- O += P . V ----
      #pragma unroll
      for(int ks2=0;ks2<2;++ks2){
        short8 pf[2];
        #pragma unroll
        for(int rt=0;rt<2;++rt)
          pf[rt] = *(const short8*)&Pls[(32*wr+16*rt+lr)*PST + 32*ks2 + 8*quad];
        #pragma unroll
        for(int ctv=0;ctv<4;++ctv){
          const int d = 64*wc + 16*ctv + lr;
          const short8 vf = *(const short8*)&VPs[d*VST + 32*ks2 + 8*quad];
          #pragma unroll
          for(int rt=0;rt<2;++rt)
            oacc[rt][ctv]=__builtin_amdgcn_mfma_f32_16x16x32_bf16(pf[rt],vf,oacc[rt][ctv],0,0,0);
        }
      }
    }

    // ---- store O ----
    #pragma unroll
    for(int rt=0;rt<2;++rt)
      #pragma unroll
      for(int ctv=0;ctv<4;++ctv)
        #pragma unroll
        for(int r=0;r<4;++r){
          const int rowg = m*64 + 32*wr + 16*rt + 4*quad + r;
          Og[(size_t)rowg*DH + 64*wc + 16*ctv + lr] = oacc[rt][ctv][r];
        }
  }
}

// ---------------- fallback (no-workspace path, R2 kernel) ----------------
#define KSTf 136
#define VSTf 36
#define PSTf 72
typedef __attribute__((ext_vector_type(4))) unsigned uint4_;

__global__ __launch_bounds__(256,2)
void rbf_attn_mfma(const float* __restrict__ qg, const float* __restrict__ kg,
                   const float* __restrict__ vg, float* __restrict__ og){
  __shared__ short    Khi[64*KSTf];
  __shared__ short    Klo[64*KSTf];
  __shared__ unsigned VP [128*VSTf];
  __shared__ short    Pls[64*PSTf];
  __shared__ float    qsq_s[64];
  __shared__ float    ksq_s[64];

  const int tid=threadIdx.x;
  const int w=tid>>6, l=tid&63;
  const int wr=w>>1, wc=w&1;
  const int quad=l>>4, lr=l&15;
  const int bh=blockIdx.x, yp=blockIdx.y;

  const float* Qg = qg + (size_t)bh*NSEQ*DH;
  const float* Kg = kg + (size_t)bh*NSEQ*DH;
  const float* Vg = vg + (size_t)bh*NSEQ*DH;
  float*       Og = og + (size_t)bh*NSEQ*DH;

  for(int pass=0;pass<2;++pass){
    const int m = pass ? (31-yp) : yp;
    __syncthreads();
    short8 qhf[2][4], qlf[2][4];
    #pragma unroll
    for(int rt=0;rt<2;++rt){
      const int grow = m*64 + 32*wr + 16*rt + lr;
      const float* qp = Qg + (size_t)grow*DH + 8*quad;
      float ss=0.f;
      #pragma unroll
      for(int ks=0;ks<4;++ks){
        float4_ a = *(const float4_*)(qp + 32*ks);
        float4_ b = *(const float4_*)(qp + 32*ks + 4);
        short8 hi, lo;
        #pragma unroll
        for(int j=0;j<4;++j){
          float fa=a[j], fb=b[j];
          short ha=f2bf(fa); hi[j]=ha;   lo[j]=f2bf(fa-bf2f(ha));
          short hb=f2bf(fb); hi[j+4]=hb; lo[j+4]=f2bf(fb-bf2f(hb));
          ss += fa*fa + fb*fb;
        }
        qhf[rt][ks]=hi; qlf[rt][ks]=lo;
      }
      ss += __shfl_xor(ss,16);
      ss += __shfl_xor(ss,32);
      if(wc==0 && quad==0) qsq_s[32*wr+16*rt+lr] = SM_SCALE*ss;
    }
    float4_ oacc[2][4];
    #pragma unroll
    for(int a=0;a<2;++a)
      #pragma unroll
      for(int b=0;b<4;++b) oacc[a][b] = (float4_)0.f;

    const int ntiles = m+1;
    for(int jt=0;jt<ntiles;++jt){
      const int jc = jt*64;
      __syncthreads();
      #pragma unroll
      for(int it=0;it<4;++it){
        const int i = tid + 256*it;
        const int row = i>>4, c0 = 8*(i&15);
        const float* kp = Kg + (size_t)(jc+row)*DH + c0;
        float4_ a = *(const float4_*)kp;
        float4_ b = *(const float4_*)(kp+4);
        short8 hi, lo;
        float ss=0.f;
        #pragma unroll
        for(int j=0;j<4;++j){
          float fa=a[j], fb=b[j];
          short ha=f2bf(fa); hi[j]=ha;   lo[j]=f2bf(fa-bf2f(ha));
          short hb=f2bf(fb); hi[j+4]=hb; lo[j+4]=f2bf(fb-bf2f(hb));
          ss += fa*fa + fb*fb;
        }
        ss += __shfl_xor(ss,1); ss += __shfl_xor(ss,2);
        ss += __shfl_xor(ss,4); ss += __shfl_xor(ss,8);
        if(lr==0) ksq_s[row] = SM_SCALE*ss;
        *(short8*)&Khi[row*KSTf + c0] = hi;
        *(short8*)&Klo[row*KSTf + c0] = lo;
      }
      #pragma unroll
      for(int it=0;it<4;++it){
        const int u = tid + 256*it;
        const int d = u & 127, jg = u >> 7;
        const float* vp = Vg + (size_t)(jc + 8*jg)*DH + d;
        float vv[8];
        #pragma unroll
        for(int jj=0;jj<8;++jj) vv[jj] = vp[(size_t)jj*DH];
        uint4_ pk;
        #pragma unroll
        for(int p2=0;p2<4;++p2)
          pk[p2] = (unsigned)(unsigned short)f2bf(vv[2*p2]) |
                   ((unsigned)(unsigned short)f2bf(vv[2*p2+1])<<16);
        *(uint4_*)&VP[d*VSTf + 4*jg] = pk;
      }
      __syncthreads();
      float4_ sacc[2][2];
      #pragma unroll
      for(int a=0;a<2;++a)
        #pragma unroll
        for(int b=0;b<2;++b) sacc[a][b] = (float4_)0.f;
      #pragma unroll
      for(int ks=0;ks<4;++ks){
        short8 khf[2], klf[2];
        #pragma unroll
        for(int ct=0;ct<2;++ct){
          const int off = (32*wc + 16*ct + lr)*KSTf + 32*ks + 8*quad;
          khf[ct] = *(const short8*)&Khi[off];
          klf[ct] = *(const short8*)&Klo[off];
        }
        #pragma unroll
        for(int rt=0;rt<2;++rt)
          #pragma unroll
          for(int ct=0;ct<2;++ct){
            sacc[rt][ct]=__builtin_amdgcn_mfma_f32_16x16x32_bf16(qhf[rt][ks],khf[ct],sacc[rt][ct],0,0,0);
            sacc[rt][ct]=__builtin_amdgcn_mfma_f32_16x16x32_bf16(qhf[rt][ks],klf[ct],sacc[rt][ct],0,0,0);
            sacc[rt][ct]=__builtin_amdgcn_mfma_f32_16x16x32_bf16(qlf[rt][ks],khf[ct],sacc[rt][ct],0,0,0);
          }
      }
      #pragma unroll
      for(int rt=0;rt<2;++rt){
        float qs[4];
        #pragma unroll
        for(int r=0;r<4;++r) qs[r]=qsq_s[32*wr+16*rt+4*quad+r];
        #pragma unroll
        for(int ct=0;ct<2;++ct){
          const float ksq = ksq_s[32*wc+16*ct+lr];
          const int colg = jc + 32*wc+16*ct+lr;
          #pragma unroll
          for(int r=0;r<4;++r){
            const int rowg = m*64 + 32*wr+16*rt+4*quad+r;
            float logit = (2.f*SM_SCALE)*sacc[rt][ct][r] - qs[r] - ksq;
            float p = (colg<=rowg)? __expf(logit) : 0.f;
            Pls[(32*wr+16*rt+4*quad+r)*PSTf + 32*wc+16*ct+lr] = f2bf(p);
          }
        }
      }
      __syncthreads();
      #pragma unroll
      for(int ks2=0;ks2<2;++ks2){
        short8 pf[2];
        #pragma unroll
        for(int rt=0;rt<2;++rt)
          pf[rt] = *(const short8*)&Pls[(32*wr+16*rt+lr)*PSTf + 32*ks2 + 8*quad];
        #pragma unroll
        for(int ctv=0;ctv<4;++ctv){
          const int d = 64*wc + 16*ctv + lr;
          const short8 vf = *(const short8*)((const short*)VP + d*(2*VSTf) + 32*ks2 + 8*quad);
          #pragma unroll
          for(int rt=0;rt<2;++rt)
            oacc[rt][ctv]=__builtin_amdgcn_mfma_f32_16x16x32_bf16(pf[rt],vf,oacc[rt][ctv],0,0,0);
        }
      }
    }
    #pragma unroll
    for(int rt=0;rt<2;++rt)
      #pragma unroll
      for(int ctv=0;ctv<4;++ctv)
        #pragma unroll
        for(int r=0;r<4;++r){
          const int rowg = m*64 + 32*wr + 16*rt + 4*quad + r;
          Og[(size_t)rowg*DH + 64*wc + 16*ctv + lr] = oacc[rt][ctv][r];
        }
  }
}

extern "C" void kernel_launch(void* const* d_in, const int* in_sizes, int n_in,
                              void* d_out, int out_size, void* d_ws, size_t ws_size,
                              hipStream_t stream) {
  const float* q = (const float*)d_in[0];
  const float* k = (const float*)d_in[1];
  const float* v = (const float*)d_in[2];
  float* out = (float*)d_out;

  const size_t nElem = (size_t)BHC*NSEQ*DH;            // 8.39M
  const size_t need  = nElem*2*sizeof(short) + (size_t)BHC*NSEQ*sizeof(float);

  if(ws_size >= need){
    short* khig = (short*)d_ws;
    short* vtg  = khig + nElem;
    float* ksqg = (float*)(vtg + nElem);
    prep_kv<<<8192, 256, 0, stream>>>(k, v, khig, vtg, ksqg);
    rbf_attn_mfma2<<<dim3(BHC,16), 256, 0, stream>>>(q, khig, vtg, ksqg, out);
  } else {
    rbf_attn_mfma<<<dim3(BHC,16), 256, 0, stream>>>(q, k, v, out);
  }
}

// Round 4
// 258.692 us; speedup vs baseline: 3.2100x; 1.0305x over previous
//
#include <hip/hip_runtime.h>
#include <math.h>

// RBF-kernel causal attention (gfx950), round 4.
// Prepass: K->bf16 row-major + ksq (coalesced); V->bf16 transposed into
//          TILE-CONTIGUOUS layout Vt[bh][jt][d][64] via LDS transpose
//          (coalesced reads AND writes — fixes R3's 118us scatter prepass).
// Main:    no K/V LDS staging at all. MFMA A/B frags load straight from
//          L2 into VGPRs (full cache-line utilization by construction),
//          K prefetched one tile ahead. LDS only for P C->A transit,
//          double-buffered -> ONE barrier per KV tile.
// S^T = K.Q^T 2-pass split bf16 (kh*qh + kh*ql); P=exp(...) causal; O=P.V.

#define NSEQ 2048
#define DH   128
#define BHC  32
#define SM_SCALE 0.08838834764831845f

typedef __attribute__((ext_vector_type(8))) short short8;
typedef __attribute__((ext_vector_type(4))) short short4_;
typedef __attribute__((ext_vector_type(4))) float float4_;

#define PST 72    // P LDS row stride (shorts): 144B, 16B-aligned b128 reads

__device__ __forceinline__ short f2bf(float x){
  union{float f; unsigned u;} a; a.f=x;
  unsigned r = a.u + 0x7fffu + ((a.u>>16)&1u);   // RNE
  return (short)(r>>16);
}
__device__ __forceinline__ float bf2f(short h){
  union{float f; unsigned u;} a; a.u=((unsigned)(unsigned short)h)<<16; return a.f;
}

// ---------------- prepass ----------------
__global__ __launch_bounds__(256)
void prep_kv2(const float* __restrict__ kg, const float* __restrict__ vg,
              short* __restrict__ khig, short* __restrict__ vtg,
              float* __restrict__ ksqg){
  __shared__ short Vls[128*68];   // transpose staging (17.4 KB)
  const int b = blockIdx.x, tid = threadIdx.x;
  if(b < 1024){
    // V transpose tile: (bh, jt) -> Vt[bh][jt][d][64], fully coalesced
    const int bh = b>>5, jt = b&31;
    const float* vb = vg + (size_t)bh*NSEQ*DH + (size_t)jt*64*DH;
    #pragma unroll
    for(int it=0; it<8; ++it){
      int idx = tid + 256*it;          // 64 j x 32 d4
      int j = idx>>5, d4 = idx&31;
      float4_ x = *(const float4_*)(vb + (size_t)j*DH + 4*d4);
      #pragma unroll
      for(int c=0;c<4;++c) Vls[(4*d4+c)*68 + j] = f2bf(x[c]);
    }
    __syncthreads();
    short* outp = vtg + (size_t)bh*NSEQ*DH + (size_t)jt*(128*64);
    #pragma unroll
    for(int it=0; it<4; ++it){
      int u = tid + 256*it;            // 128 d x 8 j-octets
      int d = u>>3, j8 = u&7;
      short8 row = *(const short8*)&Vls[d*68 + 8*j8];
      *(short8*)(outp + d*64 + 8*j8) = row;   // contiguous 16KB/tile
    }
  } else {
    // K -> bf16 + ksq (both directions coalesced)
    const int gid = (b-1024)*256 + tid;     // 0 .. 1048575
    const int row = gid >> 4, c = gid & 15;
    const float* kp = kg + (size_t)row*DH + 8*c;
    float4_ a = *(const float4_*)kp;
    float4_ bb = *(const float4_*)(kp+4);
    short8 hi; float ss = 0.f;
    #pragma unroll
    for(int j=0;j<4;++j){
      hi[j] = f2bf(a[j]); hi[j+4] = f2bf(bb[j]);
      ss += a[j]*a[j] + bb[j]*bb[j];
    }
    *(short8*)(khig + (size_t)row*DH + 8*c) = hi;
    ss += __shfl_xor(ss,1); ss += __shfl_xor(ss,2);
    ss += __shfl_xor(ss,4); ss += __shfl_xor(ss,8);
    if(c==0) ksqg[row] = SM_SCALE*ss;
  }
}

// ---------------- main kernel ----------------
__global__ __launch_bounds__(256,2)
void rbf_attn_mfma3(const float* __restrict__ qg,
                    const short* __restrict__ khig,
                    const short* __restrict__ vtg,
                    const float* __restrict__ ksqg,
                    float* __restrict__ og){
  __shared__ short Pls[2][64*PST];   // 18.4 KB total — only LDS use

  const int tid=threadIdx.x;
  const int w=tid>>6, l=tid&63;
  const int wr=w>>1, wc=w&1;
  const int quad=l>>4, lr=l&15;
  const int bh=blockIdx.x, yp=blockIdx.y;

  const float* Qg = qg   + (size_t)bh*NSEQ*DH;
  const short* Kh = khig + (size_t)bh*NSEQ*DH;
  const short* Vt = vtg  + (size_t)bh*NSEQ*DH;
  const float* Ks = ksqg + (size_t)bh*NSEQ;
  float*       Og = og   + (size_t)bh*NSEQ*DH;

  // frag base pointers (lane-fixed parts)
  const short* krow = Kh + (size_t)(32*wc+lr)*DH + 8*quad;   // + (jc+16ct)*DH + 32ks

  int pbuf = 0;
  for(int pass=0;pass<2;++pass){
    const int m = pass ? (31-yp) : yp;
    __syncthreads();   // prior pass fully done

    // ---- Q -> register frags (hi/lo bf16) + qsq ----
    short8 qhf[2][4], qlf[2][4];
    float qs_reg[2];
    #pragma unroll
    for(int rt=0;rt<2;++rt){
      const int grow = m*64 + 32*wr + 16*rt + lr;
      const float* qp = Qg + (size_t)grow*DH + 8*quad;
      float ss=0.f;
      #pragma unroll
      for(int ks=0;ks<4;++ks){
        float4_ a = *(const float4_*)(qp + 32*ks);
        float4_ b = *(const float4_*)(qp + 32*ks + 4);
        short8 hi, lo;
        #pragma unroll
        for(int j=0;j<4;++j){
          float fa=a[j], fb=b[j];
          short ha=f2bf(fa); hi[j]=ha;   lo[j]=f2bf(fa-bf2f(ha));
          short hb=f2bf(fb); hi[j+4]=hb; lo[j+4]=f2bf(fb-bf2f(hb));
          ss += fa*fa + fb*fb;
        }
        qhf[rt][ks]=hi; qlf[rt][ks]=lo;
      }
      ss += __shfl_xor(ss,16);
      ss += __shfl_xor(ss,32);
      qs_reg[rt] = SM_SCALE*ss;
    }

    float4_ oacc[2][4];
    #pragma unroll
    for(int a=0;a<2;++a)
      #pragma unroll
      for(int b=0;b<4;++b) oacc[a][b] = (float4_)0.f;

    const int ntiles = m+1;

    // preload K frags for tile 0
    short8 kf[2][4], kn[2][4];
    #pragma unroll
    for(int ct=0;ct<2;++ct)
      #pragma unroll
      for(int ks=0;ks<4;++ks)
        kf[ct][ks] = *(const short8*)(krow + (size_t)(16*ct)*DH + 32*ks);

    for(int jt=0;jt<ntiles;++jt){
      const int jc = jt*64;

      // ---- V frags for this tile (direct from L2, line-perfect) ----
      const short* vtile = Vt + (size_t)jt*(128*64) + (size_t)(64*wc+lr)*64 + 8*quad;
      short8 vf[4][2];
      #pragma unroll
      for(int ctv=0;ctv<4;++ctv)
        #pragma unroll
        for(int ks2=0;ks2<2;++ks2)
          vf[ctv][ks2] = *(const short8*)(vtile + (size_t)(16*ctv)*64 + 32*ks2);

      float4_ kq[2];
      kq[0] = *(const float4_*)(Ks + jc + 32*wc + 4*quad);
      kq[1] = *(const float4_*)(Ks + jc + 32*wc + 16 + 4*quad);

      // ---- S^T = K . Q^T (2-pass split) ----
      float4_ sacc[2][2];
      #pragma unroll
      for(int a=0;a<2;++a)
        #pragma unroll
        for(int b=0;b<2;++b) sacc[a][b] = (float4_)0.f;

      #pragma unroll
      for(int ks=0;ks<4;++ks){
        #pragma unroll
        for(int rt=0;rt<2;++rt)
          #pragma unroll
          for(int ct=0;ct<2;++ct){
            sacc[rt][ct]=__builtin_amdgcn_mfma_f32_16x16x32_bf16(kf[ct][ks],qhf[rt][ks],sacc[rt][ct],0,0,0);
            sacc[rt][ct]=__builtin_amdgcn_mfma_f32_16x16x32_bf16(kf[ct][ks],qlf[rt][ks],sacc[rt][ct],0,0,0);
          }
      }

      // ---- prefetch next K tile frags ----
      if(jt+1 < ntiles){
        #pragma unroll
        for(int ct=0;ct<2;++ct)
          #pragma unroll
          for(int ks=0;ks<4;++ks)
            kn[ct][ks] = *(const short8*)(krow + (size_t)(jc+64+16*ct)*DH + 32*ks);
      }

      // ---- exp -> P (b64 writes to double-buffered LDS) ----
      #pragma unroll
      for(int rt=0;rt<2;++rt){
        const int rowg = m*64 + 32*wr + 16*rt + lr;
        const float qs = qs_reg[rt];
        #pragma unroll
        for(int ct=0;ct<2;++ct){
          const int j0 = jc + 32*wc + 16*ct + 4*quad;
          short4_ pw;
          #pragma unroll
          for(int r=0;r<4;++r){
            float logit = (2.f*SM_SCALE)*sacc[rt][ct][r] - qs - kq[ct][r];
            float p = (j0 + r <= rowg) ? __expf(logit) : 0.f;
            pw[r] = f2bf(p);
          }
          *(short4_*)&Pls[pbuf][(32*wr+16*rt+lr)*PST + 32*wc + 16*ct + 4*quad] = pw;
        }
      }
      __syncthreads();   // the ONLY per-tile barrier

      // ---- O += P . V ----
      #pragma unroll
      for(int ks2=0;ks2<2;++ks2){
        short8 pf0 = *(const short8*)&Pls[pbuf][(32*wr+lr)*PST + 32*ks2 + 8*quad];
        short8 pf1 = *(const short8*)&Pls[pbuf][(32*wr+16+lr)*PST + 32*ks2 + 8*quad];
        #pragma unroll
        for(int ctv=0;ctv<4;++ctv){
          oacc[0][ctv]=__builtin_amdgcn_mfma_f32_16x16x32_bf16(pf0,vf[ctv][ks2],oacc[0][ctv],0,0,0);
          oacc[1][ctv]=__builtin_amdgcn_mfma_f32_16x16x32_bf16(pf1,vf[ctv][ks2],oacc[1][ctv],0,0,0);
        }
      }
      pbuf ^= 1;

      if(jt+1 < ntiles){
        #pragma unroll
        for(int ct=0;ct<2;++ct)
          #pragma unroll
          for(int ks=0;ks<4;++ks)
            kf[ct][ks] = kn[ct][ks];
      }
    }

    // ---- store O ----
    #pragma unroll
    for(int rt=0;rt<2;++rt)
      #pragma unroll
      for(int ctv=0;ctv<4;++ctv)
        #pragma unroll
        for(int r=0;r<4;++r){
          const int rowg = m*64 + 32*wr + 16*rt + 4*quad + r;
          Og[(size_t)rowg*DH + 64*wc + 16*ctv + lr] = oacc[rt][ctv][r];
        }
  }
}

// ---------------- fallback (no-workspace path, verified R2 kernel) ----------------
#define KSTf 136
#define VSTf 36
#define PSTf 72
typedef __attribute__((ext_vector_type(4))) unsigned uint4_;

__global__ __launch_bounds__(256,2)
void rbf_attn_mfma(const float* __restrict__ qg, const float* __restrict__ kg,
                   const float* __restrict__ vg, float* __restrict__ og){
  __shared__ short    Khi[64*KSTf];
  __shared__ short    Klo[64*KSTf];
  __shared__ unsigned VP [128*VSTf];
  __shared__ short    Pfb[64*PSTf];
  __shared__ float    qsq_s[64];
  __shared__ float    ksq_s[64];

  const int tid=threadIdx.x;
  const int w=tid>>6, l=tid&63;
  const int wr=w>>1, wc=w&1;
  const int quad=l>>4, lr=l&15;
  const int bh=blockIdx.x, yp=blockIdx.y;

  const float* Qg = qg + (size_t)bh*NSEQ*DH;
  const float* Kg = kg + (size_t)bh*NSEQ*DH;
  const float* Vg = vg + (size_t)bh*NSEQ*DH;
  float*       Og = og + (size_t)bh*NSEQ*DH;

  for(int pass=0;pass<2;++pass){
    const int m = pass ? (31-yp) : yp;
    __syncthreads();
    short8 qhf[2][4], qlf[2][4];
    #pragma unroll
    for(int rt=0;rt<2;++rt){
      const int grow = m*64 + 32*wr + 16*rt + lr;
      const float* qp = Qg + (size_t)grow*DH + 8*quad;
      float ss=0.f;
      #pragma unroll
      for(int ks=0;ks<4;++ks){
        float4_ a = *(const float4_*)(qp + 32*ks);
        float4_ b = *(const float4_*)(qp + 32*ks + 4);
        short8 hi, lo;
        #pragma unroll
        for(int j=0;j<4;++j){
          float fa=a[j], fb=b[j];
          short ha=f2bf(fa); hi[j]=ha;   lo[j]=f2bf(fa-bf2f(ha));
          short hb=f2bf(fb); hi[j+4]=hb; lo[j+4]=f2bf(fb-bf2f(hb));
          ss += fa*fa + fb*fb;
        }
        qhf[rt][ks]=hi; qlf[rt][ks]=lo;
      }
      ss += __shfl_xor(ss,16);
      ss += __shfl_xor(ss,32);
      if(wc==0 && quad==0) qsq_s[32*wr+16*rt+lr] = SM_SCALE*ss;
    }
    float4_ oacc[2][4];
    #pragma unroll
    for(int a=0;a<2;++a)
      #pragma unroll
      for(int b=0;b<4;++b) oacc[a][b] = (float4_)0.f;

    const int ntiles = m+1;
    for(int jt=0;jt<ntiles;++jt){
      const int jc = jt*64;
      __syncthreads();
      #pragma unroll
      for(int it=0;it<4;++it){
        const int i = tid + 256*it;
        const int row = i>>4, c0 = 8*(i&15);
        const float* kp = Kg + (size_t)(jc+row)*DH + c0;
        float4_ a = *(const float4_*)kp;
        float4_ b = *(const float4_*)(kp+4);
        short8 hi, lo;
        float ss=0.f;
        #pragma unroll
        for(int j=0;j<4;++j){
          float fa=a[j], fb=b[j];
          short ha=f2bf(fa); hi[j]=ha;   lo[j]=f2bf(fa-bf2f(ha));
          short hb=f2bf(fb); hi[j+4]=hb; lo[j+4]=f2bf(fb-bf2f(hb));
          ss += fa*fa + fb*fb;
        }
        ss += __shfl_xor(ss,1); ss += __shfl_xor(ss,2);
        ss += __shfl_xor(ss,4); ss += __shfl_xor(ss,8);
        if(lr==0) ksq_s[row] = SM_SCALE*ss;
        *(short8*)&Khi[row*KSTf + c0] = hi;
        *(short8*)&Klo[row*KSTf + c0] = lo;
      }
      #pragma unroll
      for(int it=0;it<4;++it){
        const int u = tid + 256*it;
        const int d = u & 127, jg = u >> 7;
        const float* vp = Vg + (size_t)(jc + 8*jg)*DH + d;
        float vv[8];
        #pragma unroll
        for(int jj=0;jj<8;++jj) vv[jj] = vp[(size_t)jj*DH];
        uint4_ pk;
        #pragma unroll
        for(int p2=0;p2<4;++p2)
          pk[p2] = (unsigned)(unsigned short)f2bf(vv[2*p2]) |
                   ((unsigned)(unsigned short)f2bf(vv[2*p2+1])<<16);
        *(uint4_*)&VP[d*VSTf + 4*jg] = pk;
      }
      __syncthreads();
      float4_ sacc[2][2];
      #pragma unroll
      for(int a=0;a<2;++a)
        #pragma unroll
        for(int b=0;b<2;++b) sacc[a][b] = (float4_)0.f;
      #pragma unroll
      for(int ks=0;ks<4;++ks){
        short8 khf[2], klf[2];
        #pragma unroll
        for(int ct=0;ct<2;++ct){
          const int off = (32*wc + 16*ct + lr)*KSTf + 32*ks + 8*quad;
          khf[ct] = *(const short8*)&Khi[off];
          klf[ct] = *(const short8*)&Klo[off];
        }
        #pragma unroll
        for(int rt=0;rt<2;++rt)
          #pragma unroll
          for(int ct=0;ct<2;++ct){
            sacc[rt][ct]=__builtin_amdgcn_mfma_f32_16x16x32_bf16(qhf[rt][ks],khf[ct],sacc[rt][ct],0,0,0);
            sacc[rt][ct]=__builtin_amdgcn_mfma_f32_16x16x32_bf16(qhf[rt][ks],klf[ct],sacc[rt][ct],0,0,0);
            sacc[rt][ct]=__builtin_amdgcn_mfma_f32_16x16x32_bf16(qlf[rt][ks],khf[ct],sacc[rt][ct],0,0,0);
          }
      }
      #pragma unroll
      for(int rt=0;rt<2;++rt){
        float qs[4];
        #pragma unroll
        for(int r=0;r<4;++r) qs[r]=qsq_s[32*wr+16*rt+4*quad+r];
        #pragma unroll
        for(int ct=0;ct<2;++ct){
          const float ksq = ksq_s[32*wc+16*ct+lr];
          const int colg = jc + 32*wc+16*ct+lr;
          #pragma unroll
          for(int r=0;r<4;++r){
            const int rowg = m*64 + 32*wr+16*rt+4*quad+r;
            float logit = (2.f*SM_SCALE)*sacc[rt][ct][r] - qs[r] - ksq;
            float p = (colg<=rowg)? __expf(logit) : 0.f;
            Pfb[(32*wr+16*rt+4*quad+r)*PSTf + 32*wc+16*ct+lr] = f2bf(p);
          }
        }
      }
      __syncthreads();
      #pragma unroll
      for(int ks2=0;ks2<2;++ks2){
        short8 pf[2];
        #pragma unroll
        for(int rt=0;rt<2;++rt)
          pf[rt] = *(const short8*)&Pfb[(32*wr+16*rt+lr)*PSTf + 32*ks2 + 8*quad];
        #pragma unroll
        for(int ctv=0;ctv<4;++ctv){
          const int d = 64*wc + 16*ctv + lr;
          const short8 vfb = *(const short8*)((const short*)VP + d*(2*VSTf) + 32*ks2 + 8*quad);
          #pragma unroll
          for(int rt=0;rt<2;++rt)
            oacc[rt][ctv]=__builtin_amdgcn_mfma_f32_16x16x32_bf16(pf[rt],vfb,oacc[rt][ctv],0,0,0);
        }
      }
    }
    #pragma unroll
    for(int rt=0;rt<2;++rt)
      #pragma unroll
      for(int ctv=0;ctv<4;++ctv)
        #pragma unroll
        for(int r=0;r<4;++r){
          const int rowg = m*64 + 32*wr + 16*rt + 4*quad + r;
          Og[(size_t)rowg*DH + 64*wc + 16*ctv + lr] = oacc[rt][ctv][r];
        }
  }
}

extern "C" void kernel_launch(void* const* d_in, const int* in_sizes, int n_in,
                              void* d_out, int out_size, void* d_ws, size_t ws_size,
                              hipStream_t stream) {
  const float* q = (const float*)d_in[0];
  const float* k = (const float*)d_in[1];
  const float* v = (const float*)d_in[2];
  float* out = (float*)d_out;

  const size_t nElem = (size_t)BHC*NSEQ*DH;            // 8.39M
  const size_t need  = nElem*2*sizeof(short) + (size_t)BHC*NSEQ*sizeof(float);

  if(ws_size >= need){
    short* khig = (short*)d_ws;
    short* vtg  = khig + nElem;
    float* ksqg = (float*)(vtg + nElem);
    prep_kv2<<<5120, 256, 0, stream>>>(k, v, khig, vtg, ksqg);
    rbf_attn_mfma3<<<dim3(BHC,16), 256, 0, stream>>>(q, khig, vtg, ksqg, out);
  } else {
    rbf_attn_mfma<<<dim3(BHC,16), 256, 0, stream>>>(q, k, v, out);
  }
}

// Round 5
// 209.514 us; speedup vs baseline: 3.9634x; 1.2347x over previous
//
#include <hip/hip_runtime.h>
#include <math.h>

// RBF-kernel causal attention (gfx950), round 5.
// Prepass: K -> f16 row-major + ksq(=s*|k|^2); V -> bf16 transposed
//          tile-contiguous Vt[bh][jt][128d][64j]. All fully coalesced.
// Main:    f16 single-pass S^T = K.Q^T (no split), P = exp bf16,
//          O = P.V bf16 MFMA. Wave owns 32 q-rows x full d x full j.
//          Block = 4 waves: waves 0,1 -> Q-tile s; waves 2,3 -> 31-s
//          (processed concurrently; uniform work via y->s remap).
//          K/V staged in LDS (single buffer, reg-prefetch, 2 barriers/tile),
//          P transits wave-private LDS (no barrier needed).

#define NSEQ 2048
#define DH   128
#define BHC  32
#define SM_SCALE 0.08838834764831845f

typedef __attribute__((ext_vector_type(8))) short    short8;   // bf16x8
typedef __attribute__((ext_vector_type(8))) _Float16 half8;    // f16x8
typedef __attribute__((ext_vector_type(4))) short    short4_;
typedef __attribute__((ext_vector_type(4))) float    float4_;
typedef __attribute__((ext_vector_type(4))) unsigned uint4_;
typedef __attribute__((ext_vector_type(2))) unsigned uint2_;

#define KST 136   // K LDS row stride (shorts)
#define VST 72    // V^T LDS row stride (shorts)
#define PST 72    // P LDS row stride (shorts)

__device__ __forceinline__ short f2bf(float x){
  union{float f; unsigned u;} a; a.f=x;
  unsigned r = a.u + 0x7fffu + ((a.u>>16)&1u);   // RNE
  return (short)(r>>16);
}
__device__ __forceinline__ float bf2f(short h){
  union{float f; unsigned u;} a; a.u=((unsigned)(unsigned short)h)<<16; return a.f;
}
__device__ __forceinline__ unsigned packbf(float a, float b){
  return (unsigned)(unsigned short)f2bf(a) | ((unsigned)(unsigned short)f2bf(b)<<16);
}

// ---------------- prepass ----------------
__global__ __launch_bounds__(256)
void prep_kv5(const float* __restrict__ kg, const float* __restrict__ vg,
              _Float16* __restrict__ khg, short* __restrict__ vtg,
              float* __restrict__ ksqg){
  __shared__ unsigned Vls[128*33];   // [d][j2] short2-pairs, stride 33 dw
  const int b = blockIdx.x, t = threadIdx.x;
  const int l = t & 63, wv = t >> 6;
  if(b < 1024){
    // ---- V tile (bh, jt): fp32 rows -> bf16 V^T tile-contiguous ----
    const int bh = b>>5, jt = b&31;
    const float4_* vb4 = (const float4_*)(vg + ((size_t)bh*NSEQ + (size_t)jt*64)*DH);
    #pragma unroll
    for(int i=0;i<8;++i){
      // linear-coalesced: f4 = i*256+t -> row = 8i + (t>>5), d = 4*(t&31)
      float4_ own = vb4[i*256 + t];
      float4_ par;
      par.x = __shfl_xor(own.x, 32); par.y = __shfl_xor(own.y, 32);
      par.z = __shfl_xor(own.z, 32); par.w = __shfl_xor(own.w, 32);
      const int hi = (l>>5)&1;           // row-parity bit
      unsigned w0 = hi ? packbf(par.z, own.z) : packbf(own.x, par.x);
      unsigned w1 = hi ? packbf(par.w, own.w) : packbf(own.y, par.y);
      const int dd = 4*(t&31) + 2*hi;
      const int j2 = 4*i + wv;           // row-pair index
      Vls[dd*33 + j2]     = w0;
      Vls[(dd+1)*33 + j2] = w1;
    }
    __syncthreads();
    short* outp = vtg + ((size_t)(bh*32 + jt)*DH)*64;
    #pragma unroll
    for(int it=0; it<4; ++it){
      int idx = t + 256*it;              // 0..1023
      int d = idx>>3, slot = idx&7;
      uint4_ o;
      o.x = Vls[d*33 + 4*slot];   o.y = Vls[d*33 + 4*slot+1];
      o.z = Vls[d*33 + 4*slot+2]; o.w = Vls[d*33 + 4*slot+3];
      *(uint4_*)(outp + d*64 + 8*slot) = o;
    }
  } else {
    // ---- K: fp32 -> f16 row-major + ksq ----
    const int kb = b - 1024;             // 64 rows per block
    const float4_* kb4 = (const float4_*)(kg + (size_t)kb*64*DH);
    #pragma unroll
    for(int i=0;i<8;++i){
      float4_ x = kb4[i*256 + t];        // row = 64kb + 8i + (t>>5), d = 4*(t&31)
      const int row = 64*kb + 8*i + (t>>5);
      const int d   = 4*(t&31);
      union{ _Float16 h[4]; uint2_ u; } pk;
      pk.h[0]=(_Float16)x.x; pk.h[1]=(_Float16)x.y;
      pk.h[2]=(_Float16)x.z; pk.h[3]=(_Float16)x.w;
      *(uint2_*)(khg + (size_t)row*DH + d) = pk.u;
      float ss = x.x*x.x + x.y*x.y + x.z*x.z + x.w*x.w;
      ss += __shfl_xor(ss,1);  ss += __shfl_xor(ss,2);
      ss += __shfl_xor(ss,4);  ss += __shfl_xor(ss,8);
      ss += __shfl_xor(ss,16);
      if((l&31)==0) ksqg[row] = SM_SCALE*ss;
    }
  }
}

// ---------------- main kernel ----------------
__global__ __launch_bounds__(256,2)
void rbf_attn5(const float* __restrict__ qg,
               const _Float16* __restrict__ khg,
               const short* __restrict__ vtg,
               const float* __restrict__ ksqg,
               float* __restrict__ og){
  __shared__ short Kst[64*KST];    // 17408 B (f16 bits)
  __shared__ short Vst[128*VST];   // 18432 B (bf16)
  __shared__ short Pls[4*32*PST];  // 18432 B wave-private P
  __shared__ float ksLs[64];

  const int tid=threadIdx.x;
  const int w=tid>>6, l=tid&63;
  const int quad=l>>4, lr=l&15;
  const int bh=blockIdx.x, y=blockIdx.y;
  const int s = (y<8) ? y : 23-y;              // CU-pair balance remap
  const int m_w   = (w<2) ? s : 31-s;          // this wave's Q-tile
  const int qbase = 64*m_w + 32*(w&1);
  const int mb = 31-s;                          // block loop bound

  const float*    Qg = qg   + (size_t)bh*NSEQ*DH;
  const _Float16* Kh = khg  + (size_t)bh*NSEQ*DH;
  const short*    Vt = vtg  + (size_t)bh*32*DH*64;
  const float*    Ks = ksqg + (size_t)bh*NSEQ;
  float*          Og = og   + (size_t)bh*NSEQ*DH;
  short* Pw = Pls + w*32*PST;

  // ---- Q -> f16 B-fragments (once) + qsq ----
  half8 qf[2][4];
  float qsq[2];
  #pragma unroll
  for(int rt=0;rt<2;++rt){
    const int qrow = qbase + 16*rt + lr;
    const float* qp = Qg + (size_t)qrow*DH + 8*quad;
    float ss=0.f;
    #pragma unroll
    for(int ks=0;ks<4;++ks){
      float4_ a = *(const float4_*)(qp + 32*ks);
      float4_ b = *(const float4_*)(qp + 32*ks + 4);
      half8 h;
      #pragma unroll
      for(int j=0;j<4;++j){
        h[j]   = (_Float16)a[j];
        h[j+4] = (_Float16)b[j];
        ss += a[j]*a[j] + b[j]*b[j];
      }
      qf[rt][ks]=h;
    }
    ss += __shfl_xor(ss,16);
    ss += __shfl_xor(ss,32);
    qsq[rt] = SM_SCALE*ss;
  }

  float4_ oacc[2][8];
  #pragma unroll
  for(int a=0;a<2;++a)
    #pragma unroll
    for(int b=0;b<8;++b) oacc[a][b] = (float4_)0.f;

  // ---- staging prefetch regs for jt=0 ----
  uint4_ kreg[4], vreg[4];
  float  kqreg = 0.f;
  {
    #pragma unroll
    for(int it=0;it<4;++it){
      int idx = tid + 256*it;
      int row = idx>>4, c = idx&15;
      kreg[it] = *(const uint4_*)(Kh + (size_t)row*DH + 8*c);
      int d = idx>>3, slot = idx&7;
      vreg[it] = *(const uint4_*)(Vt + (size_t)d*64 + 8*slot);
    }
    if(tid<64) kqreg = Ks[tid];
  }

  for(int jt=0; jt<=mb; ++jt){
    // ---- write staged regs -> LDS ----
    #pragma unroll
    for(int it=0;it<4;++it){
      int idx = tid + 256*it;
      int row = idx>>4, c = idx&15;
      *(uint4_*)&Kst[row*KST + 8*c] = kreg[it];
      int d = idx>>3, slot = idx&7;
      *(uint4_*)&Vst[d*VST + 8*slot] = vreg[it];
    }
    if(tid<64) ksLs[tid] = kqreg;
    __syncthreads();                       // B2: tile visible

    // ---- prefetch next tile -> regs ----
    if(jt < mb){
      const int jc2 = (jt+1)*64;
      #pragma unroll
      for(int it=0;it<4;++it){
        int idx = tid + 256*it;
        int row = idx>>4, c = idx&15;
        kreg[it] = *(const uint4_*)(Kh + (size_t)(jc2+row)*DH + 8*c);
        int d = idx>>3, slot = idx&7;
        vreg[it] = *(const uint4_*)(Vt + ((size_t)(jt+1)*DH + d)*64 + 8*slot);
      }
      if(tid<64) kqreg = Ks[jc2 + tid];
    }

    if(jt <= m_w){
      // ---- S^T = K . Q^T (f16, single pass) ----
      float4_ sacc[2][4];
      #pragma unroll
      for(int a=0;a<2;++a)
        #pragma unroll
        for(int b=0;b<4;++b) sacc[a][b] = (float4_)0.f;

      #pragma unroll
      for(int ks=0;ks<4;++ks){
        half8 kf[4];
        #pragma unroll
        for(int ct=0;ct<4;++ct)
          kf[ct] = *(const half8*)&Kst[(16*ct+lr)*KST + 32*ks + 8*quad];
        #pragma unroll
        for(int rt=0;rt<2;++rt)
          #pragma unroll
          for(int ct=0;ct<4;++ct)
            sacc[rt][ct]=__builtin_amdgcn_mfma_f32_16x16x32_f16(kf[ct],qf[rt][ks],sacc[rt][ct],0,0,0);
      }

      // ---- exp -> bf16 P (wave-private LDS, no barrier) ----
      const int jg0 = 64*jt;
      #pragma unroll
      for(int rt=0;rt<2;++rt){
        const int qrow = qbase + 16*rt + lr;
        const float qs = qsq[rt];
        #pragma unroll
        for(int ct=0;ct<4;++ct){
          float4_ kq = *(const float4_*)&ksLs[16*ct + 4*quad];
          const int j0 = jg0 + 16*ct + 4*quad;
          short4_ pw;
          #pragma unroll
          for(int r=0;r<4;++r){
            float logit = (2.f*SM_SCALE)*sacc[rt][ct][r] - qs - kq[r];
            float p = (j0 + r <= qrow) ? __expf(logit) : 0.f;
            pw[r] = f2bf(p);
          }
          *(short4_*)&Pw[(16*rt+lr)*PST + 16*ct + 4*quad] = pw;
        }
      }

      // ---- O += P . V ----
      #pragma unroll
      for(int ks2=0;ks2<2;++ks2){
        short8 pf[2];
        #pragma unroll
        for(int rt=0;rt<2;++rt)
          pf[rt] = *(const short8*)&Pw[(16*rt+lr)*PST + 32*ks2 + 8*quad];
        #pragma unroll
        for(int ctv=0;ctv<8;++ctv){
          const short8 vf = *(const short8*)&Vst[(16*ctv+lr)*VST + 32*ks2 + 8*quad];
          #pragma unroll
          for(int rt=0;rt<2;++rt)
            oacc[rt][ctv]=__builtin_amdgcn_mfma_f32_16x16x32_bf16(pf[rt],vf,oacc[rt][ctv],0,0,0);
        }
      }
    }
    __syncthreads();                       // B1: reads done before overwrite
  }

  // ---- store O ----
  #pragma unroll
  for(int rt=0;rt<2;++rt)
    #pragma unroll
    for(int ctv=0;ctv<8;++ctv)
      #pragma unroll
      for(int r=0;r<4;++r){
        const int qrow = qbase + 16*rt + 4*quad + r;
        Og[(size_t)qrow*DH + 16*ctv + lr] = oacc[rt][ctv][r];
      }
}

// ---------------- fallback (no-workspace path, verified R2 kernel) ----------------
#define KSTf 136
#define VSTf 36
#define PSTf 72

__global__ __launch_bounds__(256,2)
void rbf_attn_mfma(const float* __restrict__ qg, const float* __restrict__ kg,
                   const float* __restrict__ vg, float* __restrict__ og){
  __shared__ short    Khi[64*KSTf];
  __shared__ short    Klo[64*KSTf];
  __shared__ unsigned VP [128*VSTf];
  __shared__ short    Pfb[64*PSTf];
  __shared__ float    qsq_s[64];
  __shared__ float    ksq_s[64];

  const int tid=threadIdx.x;
  const int w=tid>>6, l=tid&63;
  const int wr=w>>1, wc=w&1;
  const int quad=l>>4, lr=l&15;
  const int bh=blockIdx.x, yp=blockIdx.y;

  const float* Qg = qg + (size_t)bh*NSEQ*DH;
  const float* Kg = kg + (size_t)bh*NSEQ*DH;
  const float* Vg = vg + (size_t)bh*NSEQ*DH;
  float*       Og = og + (size_t)bh*NSEQ*DH;

  for(int pass=0;pass<2;++pass){
    const int m = pass ? (31-yp) : yp;
    __syncthreads();
    short8 qhf[2][4], qlf[2][4];
    #pragma unroll
    for(int rt=0;rt<2;++rt){
      const int grow = m*64 + 32*wr + 16*rt + lr;
      const float* qp = Qg + (size_t)grow*DH + 8*quad;
      float ss=0.f;
      #pragma unroll
      for(int ks=0;ks<4;++ks){
        float4_ a = *(const float4_*)(qp + 32*ks);
        float4_ b = *(const float4_*)(qp + 32*ks + 4);
        short8 hi, lo;
        #pragma unroll
        for(int j=0;j<4;++j){
          float fa=a[j], fb=b[j];
          short ha=f2bf(fa); hi[j]=ha;   lo[j]=f2bf(fa-bf2f(ha));
          short hb=f2bf(fb); hi[j+4]=hb; lo[j+4]=f2bf(fb-bf2f(hb));
          ss += fa*fa + fb*fb;
        }
        qhf[rt][ks]=hi; qlf[rt][ks]=lo;
      }
      ss += __shfl_xor(ss,16);
      ss += __shfl_xor(ss,32);
      if(wc==0 && quad==0) qsq_s[32*wr+16*rt+lr] = SM_SCALE*ss;
    }
    float4_ oacc[2][4];
    #pragma unroll
    for(int a=0;a<2;++a)
      #pragma unroll
      for(int b=0;b<4;++b) oacc[a][b] = (float4_)0.f;

    const int ntiles = m+1;
    for(int jt=0;jt<ntiles;++jt){
      const int jc = jt*64;
      __syncthreads();
      #pragma unroll
      for(int it=0;it<4;++it){
        const int i = tid + 256*it;
        const int row = i>>4, c0 = 8*(i&15);
        const float* kp = Kg + (size_t)(jc+row)*DH + c0;
        float4_ a = *(const float4_*)kp;
        float4_ b = *(const float4_*)(kp+4);
        short8 hi, lo;
        float ss=0.f;
        #pragma unroll
        for(int j=0;j<4;++j){
          float fa=a[j], fb=b[j];
          short ha=f2bf(fa); hi[j]=ha;   lo[j]=f2bf(fa-bf2f(ha));
          short hb=f2bf(fb); hi[j+4]=hb; lo[j+4]=f2bf(fb-bf2f(hb));
          ss += fa*fa + fb*fb;
        }
        ss += __shfl_xor(ss,1); ss += __shfl_xor(ss,2);
        ss += __shfl_xor(ss,4); ss += __shfl_xor(ss,8);
        if(lr==0) ksq_s[row] = SM_SCALE*ss;
        *(short8*)&Khi[row*KSTf + c0] = hi;
        *(short8*)&Klo[row*KSTf + c0] = lo;
      }
      #pragma unroll
      for(int it=0;it<4;++it){
        const int u = tid + 256*it;
        const int d = u & 127, jg = u >> 7;
        const float* vp = Vg + (size_t)(jc + 8*jg)*DH + d;
        float vv[8];
        #pragma unroll
        for(int jj=0;jj<8;++jj) vv[jj] = vp[(size_t)jj*DH];
        uint4_ pk;
        #pragma unroll
        for(int p2=0;p2<4;++p2)
          pk[p2] = (unsigned)(unsigned short)f2bf(vv[2*p2]) |
                   ((unsigned)(unsigned short)f2bf(vv[2*p2+1])<<16);
        *(uint4_*)&VP[d*VSTf + 4*jg] = pk;
      }
      __syncthreads();
      float4_ sacc[2][2];
      #pragma unroll
      for(int a=0;a<2;++a)
        #pragma unroll
        for(int b=0;b<2;++b) sacc[a][b] = (float4_)0.f;
      #pragma unroll
      for(int ks=0;ks<4;++ks){
        short8 khf[2], klf[2];
        #pragma unroll
        for(int ct=0;ct<2;++ct){
          const int off = (32*wc + 16*ct + lr)*KSTf + 32*ks + 8*quad;
          khf[ct] = *(const short8*)&Khi[off];
          klf[ct] = *(const short8*)&Klo[off];
        }
        #pragma unroll
        for(int rt=0;rt<2;++rt)
          #pragma unroll
          for(int ct=0;ct<2;++ct){
            sacc[rt][ct]=__builtin_amdgcn_mfma_f32_16x16x32_bf16(qhf[rt][ks],khf[ct],sacc[rt][ct],0,0,0);
            sacc[rt][ct]=__builtin_amdgcn_mfma_f32_16x16x32_bf16(qhf[rt][ks],klf[ct],sacc[rt][ct],0,0,0);
            sacc[rt][ct]=__builtin_amdgcn_mfma_f32_16x16x32_bf16(qlf[rt][ks],khf[ct],sacc[rt][ct],0,0,0);
          }
      }
      #pragma unroll
      for(int rt=0;rt<2;++rt){
        float qs[4];
        #pragma unroll
        for(int r=0;r<4;++r) qs[r]=qsq_s[32*wr+16*rt+4*quad+r];
        #pragma unroll
        for(int ct=0;ct<2;++ct){
          const float ksq = ksq_s[32*wc+16*ct+lr];
          const int colg = jc + 32*wc+16*ct+lr;
          #pragma unroll
          for(int r=0;r<4;++r){
            const int rowg = m*64 + 32*wr+16*rt+4*quad+r;
            float logit = (2.f*SM_SCALE)*sacc[rt][ct][r] - qs[r] - ksq;
            float p = (colg<=rowg)? __expf(logit) : 0.f;
            Pfb[(32*wr+16*rt+4*quad+r)*PSTf + 32*wc+16*ct+lr] = f2bf(p);
          }
        }
      }
      __syncthreads();
      #pragma unroll
      for(int ks2=0;ks2<2;++ks2){
        short8 pf[2];
        #pragma unroll
        for(int rt=0;rt<2;++rt)
          pf[rt] = *(const short8*)&Pfb[(32*wr+16*rt+lr)*PSTf + 32*ks2 + 8*quad];
        #pragma unroll
        for(int ctv=0;ctv<4;++ctv){
          const int d = 64*wc + 16*ctv + lr;
          const short8 vfb = *(const short8*)((const short*)VP + d*(2*VSTf) + 32*ks2 + 8*quad);
          #pragma unroll
          for(int rt=0;rt<2;++rt)
            oacc[rt][ctv]=__builtin_amdgcn_mfma_f32_16x16x32_bf16(pf[rt],vfb,oacc[rt][ctv],0,0,0);
        }
      }
    }
    #pragma unroll
    for(int rt=0;rt<2;++rt)
      #pragma unroll
      for(int ctv=0;ctv<4;++ctv)
        #pragma unroll
        for(int r=0;r<4;++r){
          const int rowg = m*64 + 32*wr + 16*rt + 4*quad + r;
          Og[(size_t)rowg*DH + 64*wc + 16*ctv + lr] = oacc[rt][ctv][r];
        }
  }
}

extern "C" void kernel_launch(void* const* d_in, const int* in_sizes, int n_in,
                              void* d_out, int out_size, void* d_ws, size_t ws_size,
                              hipStream_t stream) {
  const float* q = (const float*)d_in[0];
  const float* k = (const float*)d_in[1];
  const float* v = (const float*)d_in[2];
  float* out = (float*)d_out;

  const size_t nElem = (size_t)BHC*NSEQ*DH;            // 8.39M
  const size_t need  = nElem*2*sizeof(short) + (size_t)BHC*NSEQ*sizeof(float);

  if(ws_size >= need){
    _Float16* khg = (_Float16*)d_ws;
    short*    vtg = (short*)(khg + nElem);
    float*    ksqg = (float*)(vtg + nElem);
    prep_kv5<<<2048, 256, 0, stream>>>(k, v, khg, vtg, ksqg);
    rbf_attn5<<<dim3(BHC,16), 256, 0, stream>>>(q, khg, vtg, ksqg, out);
  } else {
    rbf_attn_mfma<<<dim3(BHC,16), 256, 0, stream>>>(q, k, v, out);
  }
}